// Round 9
// baseline (106.324 us; speedup 1.0000x reference)
//
#include <hip/hip_runtime.h>
#include <hip/hip_bf16.h>

#define BB  2
#define CC  64
#define HH  256
#define WW  320
#define NNB 9
#define PIX_PER_B (NNB * HH * WW)   // 737280
#define HW (HH * WW)                // 81920

typedef unsigned int uint;

// ws layout: [0, FEATT_BYTES) bf16 featT ; then folded weights
#define FEATT_BYTES ((size_t)BB * HH * WW * 64 * sizeof(ushort))
#define NWTS 304

// folded-weight table offsets (floats)
#define OW0 0      // [16][8]
#define OB0 128    // [16]
#define OW1 144    // [8][16]
#define OB1 272    // [8]
#define OSW 280    // [8]
#define OSB 288    // [1]

// ---------------------------------------------------------------------------
// Kernel 0: fold BN into affine weights, once, into ws (global).
// ---------------------------------------------------------------------------
__global__ __launch_bounds__(64) void fw_fold(
    const float* __restrict__ conv0_w, const float* __restrict__ bn0_g,
    const float* __restrict__ bn0_b, const float* __restrict__ bn0_m,
    const float* __restrict__ bn0_v, const float* __restrict__ conv1_w,
    const float* __restrict__ bn1_g, const float* __restrict__ bn1_b,
    const float* __restrict__ bn1_m, const float* __restrict__ bn1_v,
    const float* __restrict__ sim_w, const float* __restrict__ sim_b,
    float* __restrict__ wts) {
  const int t = threadIdx.x;
  if (t < 16) {
    float a = bn0_g[t] * rsqrtf(bn0_v[t] + 1e-5f);
    wts[OB0 + t] = bn0_b[t] - bn0_m[t] * a;
#pragma unroll
    for (int g = 0; g < 8; ++g) wts[OW0 + t * 8 + g] = conv0_w[t * 8 + g] * a;
  } else if (t < 24) {
    int o = t - 16;
    float a = bn1_g[o] * rsqrtf(bn1_v[o] + 1e-5f);
    wts[OB1 + o] = bn1_b[o] - bn1_m[o] * a;
#pragma unroll
    for (int c = 0; c < 16; ++c) wts[OW1 + o * 16 + c] = conv1_w[o * 16 + c] * a;
  } else if (t < 32) {
    wts[OSW + t - 24] = sim_w[t - 24];
    if (t == 31) wts[OSB] = sim_b[0];
  }
}

// ---------------------------------------------------------------------------
// Kernel 1: transpose [B,C,H,W] fp32 -> [B,H,W,C] bf16 (channel-contiguous)
// ---------------------------------------------------------------------------
__global__ __launch_bounds__(256) void fw_transpose(const float* __restrict__ feat,
                                                    ushort* __restrict__ featT) {
  __shared__ float tile[64][65];
  const int b = blockIdx.z, h = blockIdx.y, w0 = blockIdx.x * 64;
  const int tid = threadIdx.x;
#pragma unroll
  for (int it = 0; it < 16; ++it) {
    int idx = it * 256 + tid;
    int c = idx >> 6, w = idx & 63;
    tile[c][w] = feat[((b * CC + c) * HH + h) * WW + w0 + w];
  }
  __syncthreads();
#pragma unroll
  for (int it = 0; it < 16; ++it) {
    int idx = it * 256 + tid;
    int w = idx >> 6, c = idx & 63;
    __hip_bfloat16 v = __float2bfloat16(tile[c][w]);
    featT[((b * HH + h) * WW + w0 + w) * 64 + c] = *(ushort*)&v;
  }
}

__device__ __forceinline__ float blo(uint u) { return __uint_as_float(u << 16); }
__device__ __forceinline__ float bhi(uint u) { return __uint_as_float(u & 0xffff0000u); }

// ---------------------------------------------------------------------------
// Kernel 2: center-reuse x3. Each wave owns 64 consecutive (h,w) positions
// and 3 neighbors n = 3*trip+{0,1,2}. The center/ref lines (n-independent)
// are preloaded ONCE into ctr[8] and reused across the 3 n's -> line
// requests per (h,w) drop 45 -> 39, and center L2 locality becomes perfect.
// Per n: round-7's depth-2 8-stage pipeline (4 corner lines/stage, 8-lane
// 128B clusters), 8x8 butterfly transpose, per-pixel MLP via scalar-load
// weights. XCD-pinned batches.
// ---------------------------------------------------------------------------
__global__ __launch_bounds__(256) void fw_main5(
    const ushort* __restrict__ featT, const float* __restrict__ grid,
    const float* __restrict__ wts, float* __restrict__ out) {
  // XCD pinning (round-robin dispatch: block i -> XCD i%8).
  // 1920 blocks: XCDs 0..3 -> batch 0, XCDs 4..7 -> batch 1 (bijective).
  const int blk = blockIdx.x;
  const int xcd = blk & 7;
  const int jb = blk >> 3;                  // 0..240
  const int b = xcd >> 2;
  const int lblk = jb * 4 + (xcd & 3);      // 0..960 within batch

  const int tid = threadIdx.x;
  const int lane = tid & 63;
  const int wid = tid >> 6;                 // wave in block, 0..3
  const int team = lane >> 3;               // 0..7
  const int lj = lane & 7;                  // lane-in-team = channel group

  // wave-task in [0,3840): trip-major so consecutive blocks stream
  // consecutive hw (center/grid locality on the XCD's L2).
  const int task = lblk * 4 + wid;
  const int trip = task / 1280;             // 0..2  -> n = 3*trip + r
  const int hwg = task % 1280;              // 0..1279
  const int hwbase = hwg * 64;              // wave's first (h,w)

  const ushort* __restrict__ fbT = featT + (size_t)b * ((size_t)HW * 64);

  // ---- preload center lines once: ctr[s] = pixel s*8+team, chans lj*8.. --
  uint4 ctr[8];
#pragma unroll
  for (int s = 0; s < 8; ++s)
    ctr[s] = *(const uint4*)(fbT + (hwbase + s * 8 + team) * 64 + lj * 8);

  float pc[8];   // pc[s] = group-lj corr partial of pixel s*8+team

#define PERM(S, PX, PY, PO)                                                    \
  {                                                                            \
    int src = (S)*8 + team;                                                    \
    PX = __shfl(wx, src);                                                      \
    PY = __shfl(wy, src);                                                      \
    PO = __shfl(off00, src);                                                   \
  }

#define LOADS(PO, L)                                                           \
  {                                                                            \
    const ushort* base = fbT + PO + lj * 8;                                    \
    L[0] = *(const uint4*)(base);                /* c00 */                     \
    L[1] = *(const uint4*)(base + 64);           /* c01 */                     \
    L[2] = *(const uint4*)(base + WW * 64);      /* c10 */                     \
    L[3] = *(const uint4*)(base + WW * 64 + 64); /* c11 */                     \
  }

#define CORRS(S, PX, PY, L)                                                    \
  {                                                                            \
    float e00 = (1.0f - PX) * (1.0f - PY);                                     \
    float e01 = PX * (1.0f - PY);                                              \
    float e10 = (1.0f - PX) * PY;                                              \
    float e11 = PX * PY;                                                       \
    const uint* ua = (const uint*)&L[0];                                       \
    const uint* ub = (const uint*)&L[1];                                       \
    const uint* uc = (const uint*)&L[2];                                       \
    const uint* ud = (const uint*)&L[3];                                       \
    const uint* ur = (const uint*)&ctr[S];                                     \
    float acc = 0.0f;                                                          \
    _Pragma("unroll") for (int k = 0; k < 4; ++k) {                            \
      float s0 = e00 * blo(ua[k]) + e01 * blo(ub[k]) + e10 * blo(uc[k]) +      \
                 e11 * blo(ud[k]);                                             \
      acc += s0 * blo(ur[k]);                                                  \
      float s1 = e00 * bhi(ua[k]) + e01 * bhi(ub[k]) + e10 * bhi(uc[k]) +      \
                 e11 * bhi(ud[k]);                                             \
      acc += s1 * bhi(ur[k]);                                                  \
    }                                                                          \
    pc[S] = acc * 0.125f;                                                      \
  }

  for (int r = 0; r < 3; ++r) {
    const int n = trip * 3 + r;

    // ---- owner-lane setup: pixel (n, hwbase+lane) ------------------------
    float wx, wy;
    int off00;
    {
      const int hw = hwbase + lane;
      const float2 g2 = *(const float2*)(grid +
          (size_t)2 * ((size_t)(b * NNB + n) * HW + hw));
      float ix = fminf(fmaxf(((g2.x + 1.0f) * (float)WW - 1.0f) * 0.5f, 0.0f),
                       (float)(WW - 1));
      float iy = fminf(fmaxf(((g2.y + 1.0f) * (float)HH - 1.0f) * 0.5f, 0.0f),
                       (float)(HH - 1));
      // x0=min(floor,W-2), wx=ix-x0 equals the reference's clamped bilinear
      // (at ix=W-1: wx=1, x0-corner weight 0); guarantees x1=x0+1 in-bounds.
      int x0 = min((int)floorf(ix), WW - 2);
      int y0 = min((int)floorf(iy), HH - 2);
      wx = ix - (float)x0;
      wy = iy - (float)y0;
      off00 = (y0 * WW + x0) * 64;
    }

    float pxA, pyA, pxB, pyB;
    int poA, poB;
    uint4 LA[4], LB[4];

    // depth-2 pipeline over 8 stages (round-7 proven pattern)
    PERM(0, pxA, pyA, poA) LOADS(poA, LA)
    PERM(1, pxB, pyB, poB) LOADS(poB, LB)
    CORRS(0, pxA, pyA, LA)
    PERM(2, pxA, pyA, poA) LOADS(poA, LA)
    CORRS(1, pxB, pyB, LB)
    PERM(3, pxB, pyB, poB) LOADS(poB, LB)
    CORRS(2, pxA, pyA, LA)
    PERM(4, pxA, pyA, poA) LOADS(poA, LA)
    CORRS(3, pxB, pyB, LB)
    PERM(5, pxB, pyB, poB) LOADS(poB, LB)
    CORRS(4, pxA, pyA, LA)
    PERM(6, pxA, pyA, poA) LOADS(poA, LA)
    CORRS(5, pxB, pyB, LB)
    PERM(7, pxB, pyB, poB) LOADS(poB, LB)
    CORRS(6, pxA, pyA, LA)
    CORRS(7, pxB, pyB, LB)

    // ---- 8x8 butterfly register transpose (within each 8-lane team) ------
    // pre:  lane(team,lj) slot s = group lj of pixel s*8+team
    // post: lane(team,lj) slot g = group g  of pixel lj*8+team
#pragma unroll
    for (int m = 1; m < 8; m <<= 1) {
      float tmp[8];
#pragma unroll
      for (int s = 0; s < 8; ++s) tmp[s] = pc[s];
#pragma unroll
      for (int s = 0; s < 8; ++s) {
        float rr = __shfl_xor(tmp[s ^ m], m);
        pc[s] = (((lj & m) != 0) == ((s & m) != 0)) ? tmp[s] : rr;
      }
    }

    // ---- MLP (weights: wave-uniform scalar loads) + sigmoid --------------
    float h0v[16];
#pragma unroll
    for (int o = 0; o < 16; ++o) {
      float s = wts[OB0 + o];
#pragma unroll
      for (int g = 0; g < 8; ++g) s += wts[OW0 + o * 8 + g] * pc[g];
      h0v[o] = fmaxf(s, 0.0f);
    }
    float h1v[8];
#pragma unroll
    for (int o = 0; o < 8; ++o) {
      float s = wts[OB1 + o];
#pragma unroll
      for (int c = 0; c < 16; ++c) s += wts[OW1 + o * 16 + c] * h0v[c];
      h1v[o] = fmaxf(s, 0.0f);
    }
    float s = wts[OSB];
#pragma unroll
    for (int c = 0; c < 8; ++c) s += wts[OSW + c] * h1v[c];

    out[(size_t)b * PIX_PER_B + (size_t)n * HW + hwbase + lj * 8 + team] =
        1.0f / (1.0f + __expf(-s));
  }

#undef PERM
#undef LOADS
#undef CORRS
}

// ---------------------------------------------------------------------------
// Fallback (no workspace): 1 thread per pixel, direct fp32 gathers,
// per-block LDS weight fold.
// ---------------------------------------------------------------------------
__global__ __launch_bounds__(256) void fw_main_fallback(
    const float* __restrict__ feat, const float* __restrict__ grid,
    const float* __restrict__ conv0_w, const float* __restrict__ bn0_g,
    const float* __restrict__ bn0_b, const float* __restrict__ bn0_m,
    const float* __restrict__ bn0_v, const float* __restrict__ conv1_w,
    const float* __restrict__ bn1_g, const float* __restrict__ bn1_b,
    const float* __restrict__ bn1_m, const float* __restrict__ bn1_v,
    const float* __restrict__ sim_w, const float* __restrict__ sim_b,
    float* __restrict__ out) {
  __shared__ float sW0[16 * 8], sB0[16], sW1[8 * 16], sB1[8], sSW[8], sSB[1];
  {
    const int tt = threadIdx.x;
    if (tt < 16) {
      float a = bn0_g[tt] * rsqrtf(bn0_v[tt] + 1e-5f);
      sB0[tt] = bn0_b[tt] - bn0_m[tt] * a;
#pragma unroll
      for (int g = 0; g < 8; ++g) sW0[tt * 8 + g] = conv0_w[tt * 8 + g] * a;
    } else if (tt < 24) {
      int o = tt - 16;
      float a = bn1_g[o] * rsqrtf(bn1_v[o] + 1e-5f);
      sB1[o] = bn1_b[o] - bn1_m[o] * a;
#pragma unroll
      for (int c = 0; c < 16; ++c) sW1[o * 16 + c] = conv1_w[o * 16 + c] * a;
    } else if (tt < 32) {
      sSW[tt - 24] = sim_w[tt - 24];
      if (tt == 31) sSB[0] = sim_b[0];
    }
  }
  __syncthreads();

  const int t = blockIdx.x * 256 + threadIdx.x;
  const int w = t % WW;
  const int tmp = t / WW;
  const int h = tmp & (HH - 1);
  const int nb = tmp >> 8;
  const int n = nb % NNB;
  const int b = nb / NNB;

  const float2 g2 =
      *(const float2*)(grid + (size_t)2 * (((size_t)((b * NNB + n) * HH + h)) * WW + w));
  float ix = fminf(fmaxf(((g2.x + 1.0f) * (float)WW - 1.0f) * 0.5f, 0.0f), (float)(WW - 1));
  float iy = fminf(fmaxf(((g2.y + 1.0f) * (float)HH - 1.0f) * 0.5f, 0.0f), (float)(HH - 1));
  float x0f = floorf(ix), y0f = floorf(iy);
  float wx = ix - x0f, wy = iy - y0f;
  int x0 = (int)x0f, y0 = (int)y0f;
  int x1 = min(x0 + 1, WW - 1), y1 = min(y0 + 1, HH - 1);
  float w00 = (1.0f - wx) * (1.0f - wy), w01 = wx * (1.0f - wy);
  float w10 = (1.0f - wx) * wy, w11 = wx * wy;

  float corr[8];
  const float* fbp = feat + (size_t)b * (CC * HH * WW);
#pragma unroll
  for (int g = 0; g < 8; ++g) {
    float acc = 0.0f;
    for (int ch = 0; ch < 8; ++ch) {
      const float* fc = fbp + (size_t)(g * 8 + ch) * (HH * WW);
      float sv = w00 * fc[y0 * WW + x0] + w01 * fc[y0 * WW + x1] +
                 w10 * fc[y1 * WW + x0] + w11 * fc[y1 * WW + x1];
      acc += sv * fc[h * WW + w];
    }
    corr[g] = acc * 0.125f;
  }

  float h0v[16];
#pragma unroll
  for (int o = 0; o < 16; ++o) {
    float s = sB0[o];
#pragma unroll
    for (int g = 0; g < 8; ++g) s += sW0[o * 8 + g] * corr[g];
    h0v[o] = fmaxf(s, 0.0f);
  }
  float h1v[8];
#pragma unroll
  for (int o = 0; o < 8; ++o) {
    float s = sB1[o];
#pragma unroll
    for (int c = 0; c < 16; ++c) s += sW1[o * 16 + c] * h0v[c];
    h1v[o] = fmaxf(s, 0.0f);
  }
  float s = sSB[0];
#pragma unroll
  for (int c = 0; c < 8; ++c) s += sSW[c] * h1v[c];
  out[t] = 1.0f / (1.0f + __expf(-s));
}

// ---------------------------------------------------------------------------
extern "C" void kernel_launch(void* const* d_in, const int* in_sizes, int n_in,
                              void* d_out, int out_size, void* d_ws, size_t ws_size,
                              hipStream_t stream) {
  const float* ref_feature = (const float*)d_in[0];
  const float* grid    = (const float*)d_in[1];
  const float* conv0_w = (const float*)d_in[2];
  const float* bn0_g   = (const float*)d_in[3];
  const float* bn0_b   = (const float*)d_in[4];
  const float* bn0_m   = (const float*)d_in[5];
  const float* bn0_v   = (const float*)d_in[6];
  const float* conv1_w = (const float*)d_in[7];
  const float* bn1_g   = (const float*)d_in[8];
  const float* bn1_b   = (const float*)d_in[9];
  const float* bn1_m   = (const float*)d_in[10];
  const float* bn1_v   = (const float*)d_in[11];
  const float* sim_w   = (const float*)d_in[12];
  const float* sim_b   = (const float*)d_in[13];
  float* out = (float*)d_out;

  const size_t need = FEATT_BYTES + NWTS * sizeof(float);

  if (ws_size >= need) {
    ushort* featT = (ushort*)d_ws;
    float* wts = (float*)((char*)d_ws + FEATT_BYTES);
    fw_fold<<<1, 64, 0, stream>>>(conv0_w, bn0_g, bn0_b, bn0_m, bn0_v,
                                  conv1_w, bn1_g, bn1_b, bn1_m, bn1_v,
                                  sim_w, sim_b, wts);
    fw_transpose<<<dim3(WW / 64, HH, BB), 256, 0, stream>>>(ref_feature, featT);
    // 1920 blocks x 4 waves: wave = 64 (h,w) x 3 neighbors = 192 outputs.
    // 2 batches x 960 blocks; 960*4 waves * 192 = 737,280 pixels/batch.
    fw_main5<<<1920, 256, 0, stream>>>(featT, grid, wts, out);
  } else {
    fw_main_fallback<<<BB * PIX_PER_B / 256, 256, 0, stream>>>(ref_feature, grid,
        conv0_w, bn0_g, bn0_b, bn0_m, bn0_v,
        conv1_w, bn1_g, bn1_b, bn1_m, bn1_v, sim_w, sim_b, out);
  }
}

// Round 10
// 90.477 us; speedup vs baseline: 1.1752x; 1.1752x over previous
//
#include <hip/hip_runtime.h>
#include <hip/hip_bf16.h>

#define BB  2
#define CC  64
#define HH  256
#define WW  320
#define NNB 9
#define PIX_PER_B (NNB * HH * WW)   // 737280
#define HW (HH * WW)                // 81920

typedef unsigned int uint;

// ws layout: [0, FEATT_BYTES) bf16 featT ; then folded weights
#define FEATT_BYTES ((size_t)BB * HH * WW * 64 * sizeof(ushort))
#define NWTS 304

// folded-weight table offsets (floats)
#define OW0 0      // [16][8]
#define OB0 128    // [16]
#define OW1 144    // [8][16]
#define OB1 272    // [8]
#define OSW 280    // [8]
#define OSB 288    // [1]

// ---------------------------------------------------------------------------
// Kernel 0: fold BN into affine weights, once, into ws (global).
// ---------------------------------------------------------------------------
__global__ __launch_bounds__(64) void fw_fold(
    const float* __restrict__ conv0_w, const float* __restrict__ bn0_g,
    const float* __restrict__ bn0_b, const float* __restrict__ bn0_m,
    const float* __restrict__ bn0_v, const float* __restrict__ conv1_w,
    const float* __restrict__ bn1_g, const float* __restrict__ bn1_b,
    const float* __restrict__ bn1_m, const float* __restrict__ bn1_v,
    const float* __restrict__ sim_w, const float* __restrict__ sim_b,
    float* __restrict__ wts) {
  const int t = threadIdx.x;
  if (t < 16) {
    float a = bn0_g[t] * rsqrtf(bn0_v[t] + 1e-5f);
    wts[OB0 + t] = bn0_b[t] - bn0_m[t] * a;
#pragma unroll
    for (int g = 0; g < 8; ++g) wts[OW0 + t * 8 + g] = conv0_w[t * 8 + g] * a;
  } else if (t < 24) {
    int o = t - 16;
    float a = bn1_g[o] * rsqrtf(bn1_v[o] + 1e-5f);
    wts[OB1 + o] = bn1_b[o] - bn1_m[o] * a;
#pragma unroll
    for (int c = 0; c < 16; ++c) wts[OW1 + o * 16 + c] = conv1_w[o * 16 + c] * a;
  } else if (t < 32) {
    wts[OSW + t - 24] = sim_w[t - 24];
    if (t == 31) wts[OSB] = sim_b[0];
  }
}

// ---------------------------------------------------------------------------
// Kernel 1: transpose [B,C,H,W] fp32 -> [B,H,W,C] bf16 (channel-contiguous)
// ---------------------------------------------------------------------------
__global__ __launch_bounds__(256) void fw_transpose(const float* __restrict__ feat,
                                                    ushort* __restrict__ featT) {
  __shared__ float tile[64][65];
  const int b = blockIdx.z, h = blockIdx.y, w0 = blockIdx.x * 64;
  const int tid = threadIdx.x;
#pragma unroll
  for (int it = 0; it < 16; ++it) {
    int idx = it * 256 + tid;
    int c = idx >> 6, w = idx & 63;
    tile[c][w] = feat[((b * CC + c) * HH + h) * WW + w0 + w];
  }
  __syncthreads();
#pragma unroll
  for (int it = 0; it < 16; ++it) {
    int idx = it * 256 + tid;
    int w = idx >> 6, c = idx & 63;
    __hip_bfloat16 v = __float2bfloat16(tile[c][w]);
    featT[((b * HH + h) * WW + w0 + w) * 64 + c] = *(ushort*)&v;
  }
}

__device__ __forceinline__ float blo(uint u) { return __uint_as_float(u << 16); }
__device__ __forceinline__ float bhi(uint u) { return __uint_as_float(u & 0xffff0000u); }

// ---------------------------------------------------------------------------
// Kernel 2: round-7 structure (8 lanes/pixel, depth-2 8-stage pipeline,
// 5 x 128B-line clusters per pixel, 8x8 butterfly transpose, per-pixel MLP
// via scalar-load weights) with ONE change: task ordering. Per XCD,
// task_local = jb*4+wid; hwblk = task_local/9; n = task_local%9 -> the 9
// neighbors of one 64-pixel hw-block are adjacent tasks on the SAME XCD,
// so the center lines (8 KB) are fetched into its L2 once and hit 8x.
// Concurrency stays at round-7 levels (23040 waves) -- round 9 showed the
// fetch rate is proportional to waves in flight.
// ---------------------------------------------------------------------------
__global__ __launch_bounds__(256) void fw_main6(
    const ushort* __restrict__ featT, const float* __restrict__ grid,
    const float* __restrict__ wts, float* __restrict__ out) {
  // 5760 blocks, round-robin: block i -> XCD i%8. XCDs 0..3 handle batch 0,
  // 4..7 batch 1. Per XCD: 720 blocks x 4 waves = 2880 tasks = 320 hwblk x 9 n.
  const int blk = blockIdx.x;
  const int xcd = blk & 7;
  const int jb = blk >> 3;                  // 0..719: position in XCD stream
  const int b = xcd >> 2;

  const int tid = threadIdx.x;
  const int lane = tid & 63;
  const int wid = tid >> 6;                 // wave in block, 0..3
  const int team = lane >> 3;               // 0..7
  const int lj = lane & 7;                  // lane-in-team = channel group

  const int task_local = jb * 4 + wid;      // 0..2879
  const int hwblk = (xcd & 3) * 320 + task_local / 9;  // 0..1279
  const int n = task_local % 9;
  const int wbase = hwblk * 64;             // wave's first (h,w)

  const ushort* __restrict__ fbT = featT + (size_t)b * ((size_t)HW * 64);

  // ---- owner-lane setup: sample (n, wbase+lane) --------------------------
  float wx, wy;
  int off00, offc;
  {
    const int hw = wbase + lane;
    const float2 g2 = *(const float2*)(grid +
        (size_t)2 * ((size_t)(b * NNB + n) * HW + hw));
    float ix = fminf(fmaxf(((g2.x + 1.0f) * (float)WW - 1.0f) * 0.5f, 0.0f),
                     (float)(WW - 1));
    float iy = fminf(fmaxf(((g2.y + 1.0f) * (float)HH - 1.0f) * 0.5f, 0.0f),
                     (float)(HH - 1));
    // x0=min(floor,W-2), wx=ix-x0 equals the reference's clamped bilinear
    // (at ix=W-1: wx=1, x0-corner weight 0); guarantees x1=x0+1 in-bounds.
    int x0 = min((int)floorf(ix), WW - 2);
    int y0 = min((int)floorf(iy), HH - 2);
    wx = ix - (float)x0;
    wy = iy - (float)y0;
    off00 = (y0 * WW + x0) * 64;            // element offset of corner(y0,x0)
    offc = hw * 64;                         // element offset of center (h,w)
  }

  float pc[8];   // pc[s] = group-lj corr partial of pixel s*8+team

#define PERM(S, PX, PY, PO, PQ)                                                \
  {                                                                            \
    int src = (S)*8 + team;                                                    \
    PX = __shfl(wx, src);                                                      \
    PY = __shfl(wy, src);                                                      \
    PO = __shfl(off00, src);                                                   \
    PQ = __shfl(offc, src);                                                    \
  }

#define LOADS(PO, PQ, L0, L1, L2, L3, L4)                                      \
  {                                                                            \
    const ushort* base = fbT + PO + lj * 8;                                    \
    L0 = *(const uint4*)(base);               /* c00 */                        \
    L1 = *(const uint4*)(base + 64);          /* c01 */                        \
    L2 = *(const uint4*)(base + WW * 64);     /* c10 */                        \
    L3 = *(const uint4*)(base + WW * 64 + 64);/* c11 */                        \
    L4 = *(const uint4*)(fbT + PQ + lj * 8);  /* center */                     \
  }

#define CORRS(S, PX, PY, L0, L1, L2, L3, L4)                                   \
  {                                                                            \
    float e00 = (1.0f - PX) * (1.0f - PY);                                     \
    float e01 = PX * (1.0f - PY);                                              \
    float e10 = (1.0f - PX) * PY;                                              \
    float e11 = PX * PY;                                                       \
    const uint* ua = (const uint*)&L0;                                         \
    const uint* ub = (const uint*)&L1;                                         \
    const uint* uc = (const uint*)&L2;                                         \
    const uint* ud = (const uint*)&L3;                                         \
    const uint* ur = (const uint*)&L4;                                         \
    float acc = 0.0f;                                                          \
    _Pragma("unroll") for (int k = 0; k < 4; ++k) {                            \
      float s0 = e00 * blo(ua[k]) + e01 * blo(ub[k]) + e10 * blo(uc[k]) +      \
                 e11 * blo(ud[k]);                                             \
      acc += s0 * blo(ur[k]);                                                  \
      float s1 = e00 * bhi(ua[k]) + e01 * bhi(ub[k]) + e10 * bhi(uc[k]) +      \
                 e11 * bhi(ud[k]);                                             \
      acc += s1 * bhi(ur[k]);                                                  \
    }                                                                          \
    pc[S] = acc * 0.125f;                                                      \
  }

  float pxA, pyA, pxB, pyB;
  int poA, pqA, poB, pqB;
  uint4 A0, A1, A2, A3, A4, B0, B1, B2, B3, B4;

  // depth-2 pipeline over 8 stages (round-7 proven pattern)
  PERM(0, pxA, pyA, poA, pqA) LOADS(poA, pqA, A0, A1, A2, A3, A4)
  PERM(1, pxB, pyB, poB, pqB) LOADS(poB, pqB, B0, B1, B2, B3, B4)
  CORRS(0, pxA, pyA, A0, A1, A2, A3, A4)
  PERM(2, pxA, pyA, poA, pqA) LOADS(poA, pqA, A0, A1, A2, A3, A4)
  CORRS(1, pxB, pyB, B0, B1, B2, B3, B4)
  PERM(3, pxB, pyB, poB, pqB) LOADS(poB, pqB, B0, B1, B2, B3, B4)
  CORRS(2, pxA, pyA, A0, A1, A2, A3, A4)
  PERM(4, pxA, pyA, poA, pqA) LOADS(poA, pqA, A0, A1, A2, A3, A4)
  CORRS(3, pxB, pyB, B0, B1, B2, B3, B4)
  PERM(5, pxB, pyB, poB, pqB) LOADS(poB, pqB, B0, B1, B2, B3, B4)
  CORRS(4, pxA, pyA, A0, A1, A2, A3, A4)
  PERM(6, pxA, pyA, poA, pqA) LOADS(poA, pqA, A0, A1, A2, A3, A4)
  CORRS(5, pxB, pyB, B0, B1, B2, B3, B4)
  PERM(7, pxB, pyB, poB, pqB) LOADS(poB, pqB, B0, B1, B2, B3, B4)
  CORRS(6, pxA, pyA, A0, A1, A2, A3, A4)
  CORRS(7, pxB, pyB, B0, B1, B2, B3, B4)

#undef PERM
#undef LOADS
#undef CORRS

  // ---- 8x8 butterfly register transpose (within each 8-lane team) --------
  // pre:  lane(team,lj) slot s = group lj of pixel s*8+team
  // post: lane(team,lj) slot g = group g  of pixel lj*8+team
#pragma unroll
  for (int m = 1; m < 8; m <<= 1) {
    float tmp[8];
#pragma unroll
    for (int s = 0; s < 8; ++s) tmp[s] = pc[s];
#pragma unroll
    for (int s = 0; s < 8; ++s) {
      float r = __shfl_xor(tmp[s ^ m], m);
      pc[s] = (((lj & m) != 0) == ((s & m) != 0)) ? tmp[s] : r;
    }
  }

  // ---- MLP (weights: wave-uniform scalar loads) + sigmoid ----------------
  float h0v[16];
#pragma unroll
  for (int o = 0; o < 16; ++o) {
    float s = wts[OB0 + o];
#pragma unroll
    for (int g = 0; g < 8; ++g) s += wts[OW0 + o * 8 + g] * pc[g];
    h0v[o] = fmaxf(s, 0.0f);
  }
  float h1v[8];
#pragma unroll
  for (int o = 0; o < 8; ++o) {
    float s = wts[OB1 + o];
#pragma unroll
    for (int c = 0; c < 16; ++c) s += wts[OW1 + o * 16 + c] * h0v[c];
    h1v[o] = fmaxf(s, 0.0f);
  }
  float s = wts[OSB];
#pragma unroll
  for (int c = 0; c < 8; ++c) s += wts[OSW + c] * h1v[c];

  out[(size_t)b * PIX_PER_B + (size_t)n * HW + wbase + lj * 8 + team] =
      1.0f / (1.0f + __expf(-s));
}

// ---------------------------------------------------------------------------
// Fallback (no workspace): 1 thread per pixel, direct fp32 gathers,
// per-block LDS weight fold.
// ---------------------------------------------------------------------------
__global__ __launch_bounds__(256) void fw_main_fallback(
    const float* __restrict__ feat, const float* __restrict__ grid,
    const float* __restrict__ conv0_w, const float* __restrict__ bn0_g,
    const float* __restrict__ bn0_b, const float* __restrict__ bn0_m,
    const float* __restrict__ bn0_v, const float* __restrict__ conv1_w,
    const float* __restrict__ bn1_g, const float* __restrict__ bn1_b,
    const float* __restrict__ bn1_m, const float* __restrict__ bn1_v,
    const float* __restrict__ sim_w, const float* __restrict__ sim_b,
    float* __restrict__ out) {
  __shared__ float sW0[16 * 8], sB0[16], sW1[8 * 16], sB1[8], sSW[8], sSB[1];
  {
    const int tt = threadIdx.x;
    if (tt < 16) {
      float a = bn0_g[tt] * rsqrtf(bn0_v[tt] + 1e-5f);
      sB0[tt] = bn0_b[tt] - bn0_m[tt] * a;
#pragma unroll
      for (int g = 0; g < 8; ++g) sW0[tt * 8 + g] = conv0_w[tt * 8 + g] * a;
    } else if (tt < 24) {
      int o = tt - 16;
      float a = bn1_g[o] * rsqrtf(bn1_v[o] + 1e-5f);
      sB1[o] = bn1_b[o] - bn1_m[o] * a;
#pragma unroll
      for (int c = 0; c < 16; ++c) sW1[o * 16 + c] = conv1_w[o * 16 + c] * a;
    } else if (tt < 32) {
      sSW[tt - 24] = sim_w[tt - 24];
      if (tt == 31) sSB[0] = sim_b[0];
    }
  }
  __syncthreads();

  const int t = blockIdx.x * 256 + threadIdx.x;
  const int w = t % WW;
  const int tmp = t / WW;
  const int h = tmp & (HH - 1);
  const int nb = tmp >> 8;
  const int n = nb % NNB;
  const int b = nb / NNB;

  const float2 g2 =
      *(const float2*)(grid + (size_t)2 * (((size_t)((b * NNB + n) * HH + h)) * WW + w));
  float ix = fminf(fmaxf(((g2.x + 1.0f) * (float)WW - 1.0f) * 0.5f, 0.0f), (float)(WW - 1));
  float iy = fminf(fmaxf(((g2.y + 1.0f) * (float)HH - 1.0f) * 0.5f, 0.0f), (float)(HH - 1));
  float x0f = floorf(ix), y0f = floorf(iy);
  float wx = ix - x0f, wy = iy - y0f;
  int x0 = (int)x0f, y0 = (int)y0f;
  int x1 = min(x0 + 1, WW - 1), y1 = min(y0 + 1, HH - 1);
  float w00 = (1.0f - wx) * (1.0f - wy), w01 = wx * (1.0f - wy);
  float w10 = (1.0f - wx) * wy, w11 = wx * wy;

  float corr[8];
  const float* fbp = feat + (size_t)b * (CC * HH * WW);
#pragma unroll
  for (int g = 0; g < 8; ++g) {
    float acc = 0.0f;
    for (int ch = 0; ch < 8; ++ch) {
      const float* fc = fbp + (size_t)(g * 8 + ch) * (HH * WW);
      float sv = w00 * fc[y0 * WW + x0] + w01 * fc[y0 * WW + x1] +
                 w10 * fc[y1 * WW + x0] + w11 * fc[y1 * WW + x1];
      acc += sv * fc[h * WW + w];
    }
    corr[g] = acc * 0.125f;
  }

  float h0v[16];
#pragma unroll
  for (int o = 0; o < 16; ++o) {
    float s = sB0[o];
#pragma unroll
    for (int g = 0; g < 8; ++g) s += sW0[o * 8 + g] * corr[g];
    h0v[o] = fmaxf(s, 0.0f);
  }
  float h1v[8];
#pragma unroll
  for (int o = 0; o < 8; ++o) {
    float s = sB1[o];
#pragma unroll
    for (int c = 0; c < 16; ++c) s += sW1[o * 16 + c] * h0v[c];
    h1v[o] = fmaxf(s, 0.0f);
  }
  float s = sSB[0];
#pragma unroll
  for (int c = 0; c < 8; ++c) s += sSW[c] * h1v[c];
  out[t] = 1.0f / (1.0f + __expf(-s));
}

// ---------------------------------------------------------------------------
extern "C" void kernel_launch(void* const* d_in, const int* in_sizes, int n_in,
                              void* d_out, int out_size, void* d_ws, size_t ws_size,
                              hipStream_t stream) {
  const float* ref_feature = (const float*)d_in[0];
  const float* grid    = (const float*)d_in[1];
  const float* conv0_w = (const float*)d_in[2];
  const float* bn0_g   = (const float*)d_in[3];
  const float* bn0_b   = (const float*)d_in[4];
  const float* bn0_m   = (const float*)d_in[5];
  const float* bn0_v   = (const float*)d_in[6];
  const float* conv1_w = (const float*)d_in[7];
  const float* bn1_g   = (const float*)d_in[8];
  const float* bn1_b   = (const float*)d_in[9];
  const float* bn1_m   = (const float*)d_in[10];
  const float* bn1_v   = (const float*)d_in[11];
  const float* sim_w   = (const float*)d_in[12];
  const float* sim_b   = (const float*)d_in[13];
  float* out = (float*)d_out;

  const size_t need = FEATT_BYTES + NWTS * sizeof(float);

  if (ws_size >= need) {
    ushort* featT = (ushort*)d_ws;
    float* wts = (float*)((char*)d_ws + FEATT_BYTES);
    fw_fold<<<1, 64, 0, stream>>>(conv0_w, bn0_g, bn0_b, bn0_m, bn0_v,
                                  conv1_w, bn1_g, bn1_b, bn1_m, bn1_v,
                                  sim_w, sim_b, wts);
    fw_transpose<<<dim3(WW / 64, HH, BB), 256, 0, stream>>>(ref_feature, featT);
    // 5760 blocks x 4 waves = 23040 wave-tasks (64 outputs each).
    fw_main6<<<5760, 256, 0, stream>>>(featT, grid, wts, out);
  } else {
    fw_main_fallback<<<BB * PIX_PER_B / 256, 256, 0, stream>>>(ref_feature, grid,
        conv0_w, bn0_g, bn0_b, bn0_m, bn0_v,
        conv1_w, bn1_g, bn1_b, bn1_m, bn1_v, sim_w, sim_b, out);
  }
}

// Round 11
// 89.477 us; speedup vs baseline: 1.1883x; 1.0112x over previous
//
#include <hip/hip_runtime.h>
#include <hip/hip_bf16.h>

#define BB  2
#define CC  64
#define HH  256
#define WW  320
#define NNB 9
#define PIX_PER_B (NNB * HH * WW)   // 737280
#define HW (HH * WW)                // 81920

typedef unsigned int uint;

// ws layout: [0, FEATT_BYTES) bf16 featT ; then folded weights
#define FEATT_BYTES ((size_t)BB * HH * WW * 64 * sizeof(ushort))
#define NWTS 304

// folded-weight table offsets (floats)
#define OW0 0      // [16][8]
#define OB0 128    // [16]
#define OW1 144    // [8][16]
#define OB1 272    // [8]
#define OSW 280    // [8]
#define OSB 288    // [1]

// ---------------------------------------------------------------------------
// Kernel 0: fold BN into affine weights, once, into ws (global).
// ---------------------------------------------------------------------------
__global__ __launch_bounds__(64) void fw_fold(
    const float* __restrict__ conv0_w, const float* __restrict__ bn0_g,
    const float* __restrict__ bn0_b, const float* __restrict__ bn0_m,
    const float* __restrict__ bn0_v, const float* __restrict__ conv1_w,
    const float* __restrict__ bn1_g, const float* __restrict__ bn1_b,
    const float* __restrict__ bn1_m, const float* __restrict__ bn1_v,
    const float* __restrict__ sim_w, const float* __restrict__ sim_b,
    float* __restrict__ wts) {
  const int t = threadIdx.x;
  if (t < 16) {
    float a = bn0_g[t] * rsqrtf(bn0_v[t] + 1e-5f);
    wts[OB0 + t] = bn0_b[t] - bn0_m[t] * a;
#pragma unroll
    for (int g = 0; g < 8; ++g) wts[OW0 + t * 8 + g] = conv0_w[t * 8 + g] * a;
  } else if (t < 24) {
    int o = t - 16;
    float a = bn1_g[o] * rsqrtf(bn1_v[o] + 1e-5f);
    wts[OB1 + o] = bn1_b[o] - bn1_m[o] * a;
#pragma unroll
    for (int c = 0; c < 16; ++c) wts[OW1 + o * 16 + c] = conv1_w[o * 16 + c] * a;
  } else if (t < 32) {
    wts[OSW + t - 24] = sim_w[t - 24];
    if (t == 31) wts[OSB] = sim_b[0];
  }
}

// ---------------------------------------------------------------------------
// Kernel 1: transpose [B,C,H,W] fp32 -> [B,H,W,C] bf16 (channel-contiguous)
// ---------------------------------------------------------------------------
__global__ __launch_bounds__(256) void fw_transpose(const float* __restrict__ feat,
                                                    ushort* __restrict__ featT) {
  __shared__ float tile[64][65];
  const int b = blockIdx.z, h = blockIdx.y, w0 = blockIdx.x * 64;
  const int tid = threadIdx.x;
#pragma unroll
  for (int it = 0; it < 16; ++it) {
    int idx = it * 256 + tid;
    int c = idx >> 6, w = idx & 63;
    tile[c][w] = feat[((b * CC + c) * HH + h) * WW + w0 + w];
  }
  __syncthreads();
#pragma unroll
  for (int it = 0; it < 16; ++it) {
    int idx = it * 256 + tid;
    int w = idx >> 6, c = idx & 63;
    __hip_bfloat16 v = __float2bfloat16(tile[c][w]);
    featT[((b * HH + h) * WW + w0 + w) * 64 + c] = *(ushort*)&v;
  }
}

__device__ __forceinline__ float blo(uint u) { return __uint_as_float(u << 16); }
__device__ __forceinline__ float bhi(uint u) { return __uint_as_float(u & 0xffff0000u); }

// ---------------------------------------------------------------------------
// Kernel 2: round-10 structure (8 lanes/pixel, 5 x 128B-line clusters per
// pixel, n-adjacent task remap for center L2 reuse, 8x8 butterfly transpose,
// per-pixel MLP via scalar-load weights) with ONE change: pipeline depth
// 2 -> 3 (15 outstanding lines per wave). Pinned with asm memory clobbers
// (R8 lesson: sched_barrier(0) alone lets the allocator recycle the load
// registers and collapse the pipeline; VGPR count is the tripwire).
// ---------------------------------------------------------------------------
__global__ __launch_bounds__(256) void fw_main7(
    const ushort* __restrict__ featT, const float* __restrict__ grid,
    const float* __restrict__ wts, float* __restrict__ out) {
  // 5760 blocks, round-robin: block i -> XCD i%8. XCDs 0..3 handle batch 0,
  // 4..7 batch 1. Per XCD: 720 blocks x 4 waves = 2880 tasks = 320 hwblk x 9 n.
  const int blk = blockIdx.x;
  const int xcd = blk & 7;
  const int jb = blk >> 3;                  // 0..719: position in XCD stream
  const int b = xcd >> 2;

  const int tid = threadIdx.x;
  const int lane = tid & 63;
  const int wid = tid >> 6;                 // wave in block, 0..3
  const int team = lane >> 3;               // 0..7
  const int lj = lane & 7;                  // lane-in-team = channel group

  const int task_local = jb * 4 + wid;      // 0..2879
  const int hwblk = (xcd & 3) * 320 + task_local / 9;  // 0..1279
  const int n = task_local % 9;
  const int wbase = hwblk * 64;             // wave's first (h,w)

  const ushort* __restrict__ fbT = featT + (size_t)b * ((size_t)HW * 64);

  // ---- owner-lane setup: sample (n, wbase+lane) --------------------------
  float wx, wy;
  int off00, offc;
  {
    const int hw = wbase + lane;
    const float2 g2 = *(const float2*)(grid +
        (size_t)2 * ((size_t)(b * NNB + n) * HW + hw));
    float ix = fminf(fmaxf(((g2.x + 1.0f) * (float)WW - 1.0f) * 0.5f, 0.0f),
                     (float)(WW - 1));
    float iy = fminf(fmaxf(((g2.y + 1.0f) * (float)HH - 1.0f) * 0.5f, 0.0f),
                     (float)(HH - 1));
    // x0=min(floor,W-2), wx=ix-x0 equals the reference's clamped bilinear
    // (at ix=W-1: wx=1, x0-corner weight 0); guarantees x1=x0+1 in-bounds.
    int x0 = min((int)floorf(ix), WW - 2);
    int y0 = min((int)floorf(iy), HH - 2);
    wx = ix - (float)x0;
    wy = iy - (float)y0;
    off00 = (y0 * WW + x0) * 64;            // element offset of corner(y0,x0)
    offc = hw * 64;                         // element offset of center (h,w)
  }

  float pc[8];   // pc[s] = group-lj corr partial of pixel s*8+team

#define PERM(S, PX, PY, PO, PQ)                                                \
  {                                                                            \
    int src = (S)*8 + team;                                                    \
    PX = __shfl(wx, src);                                                      \
    PY = __shfl(wy, src);                                                      \
    PO = __shfl(off00, src);                                                   \
    PQ = __shfl(offc, src);                                                    \
  }

#define LOADS(PO, PQ, L0, L1, L2, L3, L4)                                      \
  {                                                                            \
    const ushort* base = fbT + PO + lj * 8;                                    \
    L0 = *(const uint4*)(base);               /* c00 */                        \
    L1 = *(const uint4*)(base + 64);          /* c01 */                        \
    L2 = *(const uint4*)(base + WW * 64);     /* c10 */                        \
    L3 = *(const uint4*)(base + WW * 64 + 64);/* c11 */                        \
    L4 = *(const uint4*)(fbT + PQ + lj * 8);  /* center */                     \
  }

#define CORRS(S, PX, PY, L0, L1, L2, L3, L4)                                   \
  {                                                                            \
    float e00 = (1.0f - PX) * (1.0f - PY);                                     \
    float e01 = PX * (1.0f - PY);                                              \
    float e10 = (1.0f - PX) * PY;                                              \
    float e11 = PX * PY;                                                       \
    const uint* ua = (const uint*)&L0;                                         \
    const uint* ub = (const uint*)&L1;                                         \
    const uint* uc = (const uint*)&L2;                                         \
    const uint* ud = (const uint*)&L3;                                         \
    const uint* ur = (const uint*)&L4;                                         \
    float acc = 0.0f;                                                          \
    _Pragma("unroll") for (int k = 0; k < 4; ++k) {                            \
      float s0 = e00 * blo(ua[k]) + e01 * blo(ub[k]) + e10 * blo(uc[k]) +      \
                 e11 * blo(ud[k]);                                             \
      acc += s0 * blo(ur[k]);                                                  \
      float s1 = e00 * bhi(ua[k]) + e01 * bhi(ub[k]) + e10 * bhi(uc[k]) +      \
                 e11 * bhi(ud[k]);                                             \
      acc += s1 * bhi(ur[k]);                                                  \
    }                                                                          \
    pc[S] = acc * 0.125f;                                                      \
  }

// compiler-level fence: loads may not sink across (memory clobber), and the
// MI scheduler may not reorder across (sched_barrier).
#define PIN()                                                                  \
  asm volatile("" ::: "memory");                                               \
  __builtin_amdgcn_sched_barrier(0);

  float pxA, pyA, pxB, pyB, pxC, pyC;
  int poA, pqA, poB, pqB, poC, pqC;
  uint4 A0, A1, A2, A3, A4, B0, B1, B2, B3, B4, C0, C1, C2, C3, C4;

  // ---- prologue: 3 stage-buffers in flight (15 lines) --------------------
  PERM(0, pxA, pyA, poA, pqA) LOADS(poA, pqA, A0, A1, A2, A3, A4)
  PERM(1, pxB, pyB, poB, pqB) LOADS(poB, pqB, B0, B1, B2, B3, B4)
  PERM(2, pxC, pyC, poC, pqC) LOADS(poC, pqC, C0, C1, C2, C3, C4)
  PIN()

  // ---- steady state: consume stage s, refill its buffer with stage s+3 ---
  CORRS(0, pxA, pyA, A0, A1, A2, A3, A4)
  PERM(3, pxA, pyA, poA, pqA) LOADS(poA, pqA, A0, A1, A2, A3, A4)
  PIN()
  CORRS(1, pxB, pyB, B0, B1, B2, B3, B4)
  PERM(4, pxB, pyB, poB, pqB) LOADS(poB, pqB, B0, B1, B2, B3, B4)
  PIN()
  CORRS(2, pxC, pyC, C0, C1, C2, C3, C4)
  PERM(5, pxC, pyC, poC, pqC) LOADS(poC, pqC, C0, C1, C2, C3, C4)
  PIN()
  CORRS(3, pxA, pyA, A0, A1, A2, A3, A4)
  PERM(6, pxA, pyA, poA, pqA) LOADS(poA, pqA, A0, A1, A2, A3, A4)
  PIN()
  CORRS(4, pxB, pyB, B0, B1, B2, B3, B4)
  PERM(7, pxB, pyB, poB, pqB) LOADS(poB, pqB, B0, B1, B2, B3, B4)
  PIN()
  CORRS(5, pxC, pyC, C0, C1, C2, C3, C4)
  CORRS(6, pxA, pyA, A0, A1, A2, A3, A4)
  CORRS(7, pxB, pyB, B0, B1, B2, B3, B4)

#undef PERM
#undef LOADS
#undef CORRS
#undef PIN

  // ---- 8x8 butterfly register transpose (within each 8-lane team) --------
  // pre:  lane(team,lj) slot s = group lj of pixel s*8+team
  // post: lane(team,lj) slot g = group g  of pixel lj*8+team
#pragma unroll
  for (int m = 1; m < 8; m <<= 1) {
    float tmp[8];
#pragma unroll
    for (int s = 0; s < 8; ++s) tmp[s] = pc[s];
#pragma unroll
    for (int s = 0; s < 8; ++s) {
      float r = __shfl_xor(tmp[s ^ m], m);
      pc[s] = (((lj & m) != 0) == ((s & m) != 0)) ? tmp[s] : r;
    }
  }

  // ---- MLP (weights: wave-uniform scalar loads) + sigmoid ----------------
  float h0v[16];
#pragma unroll
  for (int o = 0; o < 16; ++o) {
    float s = wts[OB0 + o];
#pragma unroll
    for (int g = 0; g < 8; ++g) s += wts[OW0 + o * 8 + g] * pc[g];
    h0v[o] = fmaxf(s, 0.0f);
  }
  float h1v[8];
#pragma unroll
  for (int o = 0; o < 8; ++o) {
    float s = wts[OB1 + o];
#pragma unroll
    for (int c = 0; c < 16; ++c) s += wts[OW1 + o * 16 + c] * h0v[c];
    h1v[o] = fmaxf(s, 0.0f);
  }
  float s = wts[OSB];
#pragma unroll
  for (int c = 0; c < 8; ++c) s += wts[OSW + c] * h1v[c];

  out[(size_t)b * PIX_PER_B + (size_t)n * HW + wbase + lj * 8 + team] =
      1.0f / (1.0f + __expf(-s));
}

// ---------------------------------------------------------------------------
// Fallback (no workspace): 1 thread per pixel, direct fp32 gathers,
// per-block LDS weight fold.
// ---------------------------------------------------------------------------
__global__ __launch_bounds__(256) void fw_main_fallback(
    const float* __restrict__ feat, const float* __restrict__ grid,
    const float* __restrict__ conv0_w, const float* __restrict__ bn0_g,
    const float* __restrict__ bn0_b, const float* __restrict__ bn0_m,
    const float* __restrict__ bn0_v, const float* __restrict__ conv1_w,
    const float* __restrict__ bn1_g, const float* __restrict__ bn1_b,
    const float* __restrict__ bn1_m, const float* __restrict__ bn1_v,
    const float* __restrict__ sim_w, const float* __restrict__ sim_b,
    float* __restrict__ out) {
  __shared__ float sW0[16 * 8], sB0[16], sW1[8 * 16], sB1[8], sSW[8], sSB[1];
  {
    const int tt = threadIdx.x;
    if (tt < 16) {
      float a = bn0_g[tt] * rsqrtf(bn0_v[tt] + 1e-5f);
      sB0[tt] = bn0_b[tt] - bn0_m[tt] * a;
#pragma unroll
      for (int g = 0; g < 8; ++g) sW0[tt * 8 + g] = conv0_w[tt * 8 + g] * a;
    } else if (tt < 24) {
      int o = tt - 16;
      float a = bn1_g[o] * rsqrtf(bn1_v[o] + 1e-5f);
      sB1[o] = bn1_b[o] - bn1_m[o] * a;
#pragma unroll
      for (int c = 0; c < 16; ++c) sW1[o * 16 + c] = conv1_w[o * 16 + c] * a;
    } else if (tt < 32) {
      sSW[tt - 24] = sim_w[tt - 24];
      if (tt == 31) sSB[0] = sim_b[0];
    }
  }
  __syncthreads();

  const int t = blockIdx.x * 256 + threadIdx.x;
  const int w = t % WW;
  const int tmp = t / WW;
  const int h = tmp & (HH - 1);
  const int nb = tmp >> 8;
  const int n = nb % NNB;
  const int b = nb / NNB;

  const float2 g2 =
      *(const float2*)(grid + (size_t)2 * (((size_t)((b * NNB + n) * HH + h)) * WW + w));
  float ix = fminf(fmaxf(((g2.x + 1.0f) * (float)WW - 1.0f) * 0.5f, 0.0f), (float)(WW - 1));
  float iy = fminf(fmaxf(((g2.y + 1.0f) * (float)HH - 1.0f) * 0.5f, 0.0f), (float)(HH - 1));
  float x0f = floorf(ix), y0f = floorf(iy);
  float wx = ix - x0f, wy = iy - y0f;
  int x0 = (int)x0f, y0 = (int)y0f;
  int x1 = min(x0 + 1, WW - 1), y1 = min(y0 + 1, HH - 1);
  float w00 = (1.0f - wx) * (1.0f - wy), w01 = wx * (1.0f - wy);
  float w10 = (1.0f - wx) * wy, w11 = wx * wy;

  float corr[8];
  const float* fbp = feat + (size_t)b * (CC * HH * WW);
#pragma unroll
  for (int g = 0; g < 8; ++g) {
    float acc = 0.0f;
    for (int ch = 0; ch < 8; ++ch) {
      const float* fc = fbp + (size_t)(g * 8 + ch) * (HH * WW);
      float sv = w00 * fc[y0 * WW + x0] + w01 * fc[y0 * WW + x1] +
                 w10 * fc[y1 * WW + x0] + w11 * fc[y1 * WW + x1];
      acc += sv * fc[h * WW + w];
    }
    corr[g] = acc * 0.125f;
  }

  float h0v[16];
#pragma unroll
  for (int o = 0; o < 16; ++o) {
    float s = sB0[o];
#pragma unroll
    for (int g = 0; g < 8; ++g) s += sW0[o * 8 + g] * corr[g];
    h0v[o] = fmaxf(s, 0.0f);
  }
  float h1v[8];
#pragma unroll
  for (int o = 0; o < 8; ++o) {
    float s = sB1[o];
#pragma unroll
    for (int c = 0; c < 16; ++c) s += sW1[o * 16 + c] * h0v[c];
    h1v[o] = fmaxf(s, 0.0f);
  }
  float s = sSB[0];
#pragma unroll
  for (int c = 0; c < 8; ++c) s += sSW[c] * h1v[c];
  out[t] = 1.0f / (1.0f + __expf(-s));
}

// ---------------------------------------------------------------------------
extern "C" void kernel_launch(void* const* d_in, const int* in_sizes, int n_in,
                              void* d_out, int out_size, void* d_ws, size_t ws_size,
                              hipStream_t stream) {
  const float* ref_feature = (const float*)d_in[0];
  const float* grid    = (const float*)d_in[1];
  const float* conv0_w = (const float*)d_in[2];
  const float* bn0_g   = (const float*)d_in[3];
  const float* bn0_b   = (const float*)d_in[4];
  const float* bn0_m   = (const float*)d_in[5];
  const float* bn0_v   = (const float*)d_in[6];
  const float* conv1_w = (const float*)d_in[7];
  const float* bn1_g   = (const float*)d_in[8];
  const float* bn1_b   = (const float*)d_in[9];
  const float* bn1_m   = (const float*)d_in[10];
  const float* bn1_v   = (const float*)d_in[11];
  const float* sim_w   = (const float*)d_in[12];
  const float* sim_b   = (const float*)d_in[13];
  float* out = (float*)d_out;

  const size_t need = FEATT_BYTES + NWTS * sizeof(float);

  if (ws_size >= need) {
    ushort* featT = (ushort*)d_ws;
    float* wts = (float*)((char*)d_ws + FEATT_BYTES);
    fw_fold<<<1, 64, 0, stream>>>(conv0_w, bn0_g, bn0_b, bn0_m, bn0_v,
                                  conv1_w, bn1_g, bn1_b, bn1_m, bn1_v,
                                  sim_w, sim_b, wts);
    fw_transpose<<<dim3(WW / 64, HH, BB), 256, 0, stream>>>(ref_feature, featT);
    // 5760 blocks x 4 waves = 23040 wave-tasks (64 outputs each).
    fw_main7<<<5760, 256, 0, stream>>>(featT, grid, wts, out);
  } else {
    fw_main_fallback<<<BB * PIX_PER_B / 256, 256, 0, stream>>>(ref_feature, grid,
        conv0_w, bn0_g, bn0_b, bn0_m, bn0_v,
        conv1_w, bn1_g, bn1_b, bn1_m, bn1_v, sim_w, sim_b, out);
  }
}